// Round 2
// baseline (304.574 us; speedup 1.0000x reference)
//
#include <hip/hip_runtime.h>
#include <hip/hip_bf16.h>

// LSTM B=8192,T=512,I=3,H=25 + linear[H->1], bf16 MFMA 16x16x32.
// R14: PHASE-STAGGERED dual chains. R13 post-mortem: pk-fusing chains A,B
// into one instruction stream left the barrier->LDS-burst->MFMA->acts chain
// (~490cy) fully exposed every period (period 940 = 446 issue + 494 chain).
// Fix: stagger the chains by one barrier phase:
//   phase 2t:   compute A(t) from reg-resident fA, ISSUE ds_read of B(t)
//   phase 2t+1: compute B(t) from fB (arrived during phase A), issue read A(t+1)
// Every post-barrier region starts with register-ready compute; the ~160cy
// read latency is covered by the other chain's ~200cy compute.
// Also:
//  - fragment-linear hb layout: lane reads 16B at lane*16 (exact MFMA B-frag
//    order) -> linear 1KB wave read, zero read bank conflicts (was 116cy/step)
//  - x staged fully up-front into 128KB LDS (no restage boundaries); 136KB
//    total LDS also hardware-forces 1 block/CU (no pile-up)
//  - per-phase act glue = R12's within-chain pk (cross-chain pk impossible
//    when staggered)
// Kept: unmasked pad-slot h-writes (u=25..27 -> k=29..31, A=0), register A-frag.

#define TSTEPS 512
#define ISZ 3
#define HSZ 25
#define NW 7

typedef __attribute__((ext_vector_type(8))) short bf16x8;
typedef __attribute__((ext_vector_type(4))) float f32x4;
typedef __attribute__((ext_vector_type(2))) float v2f;

__device__ __forceinline__ unsigned short bf16_bits(float v) {
    return __builtin_bit_cast(unsigned short, __float2bfloat16(v));
}
__device__ __forceinline__ unsigned int pack_bf16(float lo, float hi) {
    return ((unsigned int)bf16_bits(hi) << 16) | (unsigned int)bf16_bits(lo);
}

__global__ __launch_bounds__(NW * 64) void lstm_mfma(
    const float* __restrict__ x,      // [B, T, I]
    const float* __restrict__ w_ih,   // [4H, I]
    const float* __restrict__ w_hh,   // [4H, H]
    const float* __restrict__ b_ih,   // [4H]
    const float* __restrict__ b_hh,   // [4H]
    const float* __restrict__ w_lin,  // [1, H]
    const float* __restrict__ b_lin,  // [1]
    float* __restrict__ out)          // [B, 1]
{
    __shared__ uint2 xpk[2][TSTEPS][16];   // 128 KB: all x, both chains
    __shared__ short hb[2][2][512];        // [chain][parity][lane*8+j] frag-linear
    __shared__ float outred[NW][32];

    const int tid  = threadIdx.x;
    const int w    = tid >> 6;       // wave 0..6: rows 16w..16w+15
    const int lane = tid & 63;
    const int n    = lane & 15;      // batch within tile
    const int q    = lane >> 4;      // quad -> unit u = 4w + q
    const int u    = 4 * w + q;
    const bool isxfA = (w == 3) && (q == 1);   // x-feed lanes, chain A
    const bool isxfB = (w == 3) && (q == 2);   // x-feed lanes, chain B

    // zero both parities of both chains (h(0)=0; x slots seeded below)
    for (int i = tid; i < 2 * 2 * 512; i += NW * 64) ((short*)hb)[i] = 0;

    // ---- stage ALL 512 steps of x (pre-packed bf16), 256 threads ----
    if (tid < 256) {
        const int bsel = tid >> 4, sub16 = tid & 15;
        #pragma unroll 1
        for (int cch = 0; cch < 2; ++cch) {
            const float* __restrict__ g =
                x + (size_t)(blockIdx.x * 32 + cch * 16 + bsel) * (TSTEPS * ISZ);
            #pragma unroll 2
            for (int it = 0; it < TSTEPS / 64; ++it) {
                const int tg = sub16 + 16 * it;        // 4-step groups 0..127
                const float4* f4 = (const float4*)(g + tg * 12);
                float4 a = f4[0], b4 = f4[1], c4 = f4[2];
                const float s[4][3] = { {a.x, a.y, a.z}, {a.w, b4.x, b4.y},
                                        {b4.z, b4.w, c4.x}, {c4.y, c4.z, c4.w} };
                #pragma unroll
                for (int uu = 0; uu < 4; ++uu) {
                    uint2 d;
                    d.x = pack_bf16(s[uu][0], s[uu][1]);
                    d.y = pack_bf16(s[uu][2], 1.0f);
                    xpk[cch][tg * 4 + uu][bsel] = d;
                }
            }
        }
    }

    // ---- register-resident A fragment (shared by both chains) ----
    // A[r=16w+n][k=q*8+j]; row r=4u'+g; k: [w_ih 0..2, bias 3, w_hh 4..28]
    bf16x8 afrag;
    #pragma unroll
    for (int j = 0; j < 8; ++j) {
        const int k = q * 8 + j;
        const int r = 16 * w + n;
        const int uu = r >> 2, g = r & 3;
        float v = 0.0f;
        if (uu < HSZ) {
            const int orow = g * HSZ + uu;             // original i,f,g,o order
            if (k < ISZ)            v = w_ih[orow * ISZ + k];
            else if (k == ISZ)      v = b_ih[orow] + b_hh[orow];
            else if (k < 4 + HSZ)   v = w_hh[orow * HSZ + (k - 4)];
        }
        afrag[j] = (short)bf16_bits(v);
    }

    __syncthreads();
    // seed x(0) into parity-0 of both chains (frag-linear k=0..3 -> idx n*8)
    if (isxfA) *(uint2*)&hb[0][0][n * 8] = xpk[0][0][n];
    if (isxfB) *(uint2*)&hb[1][0][n * 8] = xpk[1][0][n];
    __syncthreads();

    float cA = 0.f, hA = 0.f, cB = 0.f, hB = 0.f;
    const int rdoff = lane * 8;                        // shorts: B-frag linear
    const int kk = u + 4;                              // k-slot this lane writes
    const int wroff = (n + 16 * (kk >> 3)) * 8 + (kk & 7);  // u<=27 -> k<=31 pad
    const float K1 = 1.442695040888963f;               // log2 e
    const float K2 = 2.885390081777927f;               // 2 log2 e

    // prime chain A's fragment (h(0), x(0))
    bf16x8 fA = *reinterpret_cast<const bf16x8*>(&hb[0][0][rdoff]);

    auto act = [&](const f32x4 acc, float& c, float& h) {
        v2f p01 = (v2f){acc[0], acc[1]} * (v2f){-K1, -K1};
        v2f p23 = (v2f){acc[2], acc[3]} * (v2f){-K2, -K1};
        const float e0 = __builtin_amdgcn_exp2f(p01.x);
        const float e1 = __builtin_amdgcn_exp2f(p01.y);
        const float e2 = __builtin_amdgcn_exp2f(fminf(p23.x, 126.0f));
        const float e3 = __builtin_amdgcn_exp2f(p23.y);
        v2f s02 = (v2f){e0, e2} + (v2f){1.0f, 1.0f};
        v2f s13 = (v2f){e1, e3} + (v2f){1.0f, 1.0f};
        const float f  = __builtin_amdgcn_rcpf(s13.x);
        const float ig = (1.0f - e2) * __builtin_amdgcn_rcpf(s02.x * s02.y);
        c = fmaf(f, c, ig);
        const float ec = __builtin_amdgcn_exp2f(fminf(-K2 * c, 126.0f));
        h = (1.0f - ec) * __builtin_amdgcn_rcpf(s13.y * (1.0f + ec));
    };

    auto step2 = [&](int t, int rp, int wp) {
        // ---- phase A: issue read B(t); compute A(t) from fA (in regs) ----
        bf16x8 fB = *reinterpret_cast<const bf16x8*>(&hb[1][rp][rdoff]);
        const f32x4 aA = __builtin_amdgcn_mfma_f32_16x16x32_bf16(
            afrag, fA, (f32x4){0.f, 0.f, 0.f, 0.f}, 0, 0, 0);
        act(aA, cA, hA);
        hb[0][wp][wroff] = (short)bf16_bits(hA);       // unmasked pad-slot trick
        if (isxfA) *(uint2*)&hb[0][wp][n * 8] = xpk[0][(t + 1) & (TSTEPS - 1)][n];
        __syncthreads();
        // ---- phase B: issue read A(t+1); compute B(t) from fB ----
        fA = *reinterpret_cast<const bf16x8*>(&hb[0][wp][rdoff]);
        const f32x4 aB = __builtin_amdgcn_mfma_f32_16x16x32_bf16(
            afrag, fB, (f32x4){0.f, 0.f, 0.f, 0.f}, 0, 0, 0);
        act(aB, cB, hB);
        hb[1][wp][wroff] = (short)bf16_bits(hB);
        if (isxfB) *(uint2*)&hb[1][wp][n * 8] = xpk[1][(t + 1) & (TSTEPS - 1)][n];
        __syncthreads();
    };

    #pragma unroll 1
    for (int p = 0; p < TSTEPS / 2; ++p) {
        step2(2 * p,     0, 1);
        step2(2 * p + 1, 1, 0);
    }

    // ---- final linear: out[b] = sum_u w_lin[u]*h[u] + b_lin, both chains ----
    const float wl = (u < HSZ) ? w_lin[u] : 0.0f;
    float vA = wl * hA, vB = wl * hB;
    vA += __shfl_xor(vA, 16);
    vB += __shfl_xor(vB, 16);
    vA += __shfl_xor(vA, 32);
    vB += __shfl_xor(vB, 32);
    if (lane < 16) {
        outred[w][lane]      = vA;     // chain A -> batches 0..15
        outred[w][16 + lane] = vB;     // chain B -> batches 16..31
    }
    __syncthreads();
    if (tid < 32) {
        float s = b_lin[0];
        #pragma unroll
        for (int k = 0; k < NW; ++k) s += outred[k][tid];
        out[blockIdx.x * 32 + tid] = s;
    }
}

extern "C" void kernel_launch(void* const* d_in, const int* in_sizes, int n_in,
                              void* d_out, int out_size, void* d_ws, size_t ws_size,
                              hipStream_t stream) {
    const float* x     = (const float*)d_in[0];
    const float* w_ih  = (const float*)d_in[1];
    const float* w_hh  = (const float*)d_in[2];
    const float* b_ih  = (const float*)d_in[3];
    const float* b_hh  = (const float*)d_in[4];
    const float* w_lin = (const float*)d_in[5];
    const float* b_lin = (const float*)d_in[6];
    float* out = (float*)d_out;

    lstm_mfma<<<8192 / 32, NW * 64, 0, stream>>>(x, w_ih, w_hh, b_ih, b_hh,
                                                 w_lin, b_lin, out);
}